// Round 16
// baseline (3934.985 us; speedup 1.0000x reference)
//
#include <hip/hip_runtime.h>
#include <math.h>

#define BATCH 10
#define HID 128
#define OUT 7
#define MAXLEN 2048
#define NG 512
#define NT 1024
#define RINGD 512
#define OFF_STATE ((size_t)BATCH * MAXLEN * OUT)

typedef _Float16 half8 __attribute__((ext_vector_type(8)));
typedef float float4v __attribute__((ext_vector_type(4)));

__device__ __forceinline__ float sigm_(float x) { return 1.0f / (1.0f + __expf(-x)); }
__device__ __forceinline__ float tanh_(float x) { return 1.0f - 2.0f / (1.0f + __expf(2.0f * x)); }

__global__
__attribute__((amdgpu_flat_work_group_size(NT, NT), amdgpu_waves_per_eu(4, 4)))
void decoder_rnn_kernel(const float* __restrict__ h0,
                        const float* __restrict__ c0,
                        const float* __restrict__ tonehot,   // (MAXLEN+1, 1, OUT)
                        const void*  __restrict__ tf_raw,    // bool mask, int8 or int32
                        const float* __restrict__ Wih,       // (4H, OUT)
                        const float* __restrict__ Whh,       // (4H, H)
                        const float* __restrict__ bih,
                        const float* __restrict__ bhh,
                        const float* __restrict__ Wout,      // (OUT, H)
                        const float* __restrict__ bout,
                        float* __restrict__ out)
{
    // 1 chain per block. Unit-grouped MFMA: wave wv owns all 4 gates of units
    // wv*8..wv*8+7 -> gates never leave registers; 16-wave pointwise via shfl.
    __shared__ __align__(16) _Float16 h16s[2][HID];      // h hi/lo f16 split
    __shared__ float wih_eff[OUT * NG];                  // Wih^T + bias, [x][g]
    __shared__ float ring[RINGD][OUT];                   // raw biased logits
    __shared__ float lp[2][8];                           // logits K-partials
    __shared__ unsigned char tgt8[MAXLEN];
    __shared__ unsigned char tf8[MAXLEN];
    __shared__ int tf_byte_mode;

    const int t    = threadIdx.x;
    const int lane = t & 63;
    const int wv   = t >> 6;       // wave 0..15
    const int quad = lane >> 4;
    const int mrow = lane & 15;
    const int m    = mrow & 7;
    const int u    = wv * 8 + m;   // hidden unit this lane updates
    const int b    = blockIdx.x;

    // gate columns of this lane's B fragments (unit-grouped):
    // tile0: cols = i-gates u0..u0+7 then f-gates; tile1: g-gates then o-gates
    const int gc0 = (mrow < 8) ? (wv * 8 + mrow) : (HID + wv * 8 + (mrow - 8));
    const int gc1 = (mrow < 8) ? (2 * HID + wv * 8 + mrow) : (3 * HID + wv * 8 + (mrow - 8));

    // ---- B-fragments (W_hh) in registers, f16 hi/lo split (R14/R15-verified) ----
    half8 B0hi[4], B0lo[4], B1hi[4], B1lo[4];
    #pragma unroll
    for (int kc = 0; kc < 4; kc++) {
        const int kb = kc * 32 + quad * 8;
        const float* p0 = Whh + (size_t)gc0 * HID + kb;
        const float* p1 = Whh + (size_t)gc1 * HID + kb;
        #pragma unroll
        for (int j = 0; j < 8; j++) {
            float w0 = p0[j];
            _Float16 w0h = (_Float16)w0;
            B0hi[kc][j] = w0h;
            B0lo[kc][j] = (_Float16)(w0 - (float)w0h);
            float w1 = p1[j];
            _Float16 w1h = (_Float16)w1;
            B1hi[kc][j] = w1h;
            B1lo[kc][j] = (_Float16)(w1 - (float)w1h);
        }
    }
    // logits B-tile (Wout rows as cols 0..6), K-split: wave0 kc 0-1, wave1 kc 2-3
    half8 BLhi[2], BLlo[2];
    {
        #pragma unroll
        for (int c = 0; c < 2; c++)
            #pragma unroll
            for (int j = 0; j < 8; j++) { BLhi[c][j] = (_Float16)0; BLlo[c][j] = (_Float16)0; }
        if (wv < 2 && mrow < OUT) {
            #pragma unroll
            for (int c = 0; c < 2; c++) {
                const int kb = (wv * 2 + c) * 32 + quad * 8;
                const float* p = Wout + (size_t)mrow * HID + kb;
                #pragma unroll
                for (int j = 0; j < 8; j++) {
                    float w = p[j];
                    _Float16 wh = (_Float16)w;
                    BLhi[c][j] = wh;
                    BLlo[c][j] = (_Float16)(w - (float)wh);
                }
            }
        }
    }

    float boutr[OUT];
    #pragma unroll
    for (int j = 0; j < OUT; j++) boutr[j] = bout[j];

    // ---- LDS setup ----
    for (int idx = t; idx < OUT * NG; idx += NT) {
        int x = idx >> 9, g = idx & (NG - 1);
        wih_eff[idx] = Wih[g * OUT + x] + bih[g] + bhh[g];
    }
    if (t == 0) tf_byte_mode = 0;
    for (int s = t; s < MAXLEN; s += NT) {
        const float* row = tonehot + (size_t)(s + 1) * OUT;
        int idx = 0;
        #pragma unroll
        for (int j = 0; j < OUT; j++) if (row[j] > 0.5f) idx = j;
        tgt8[s] = (unsigned char)idx;
    }
    __syncthreads();
    {   // tf_mask layout detection (int8 bool vs int32) — proven R1-R15
        const unsigned char* tb = (const unsigned char*)tf_raw;
        int mis = 0;
        for (int p = t; p < MAXLEN; p += NT)
            if ((p & 3) && tb[p]) mis = 1;
        if (mis) atomicOr(&tf_byte_mode, 1);
    }
    // ---- state init: every lane holds its unit's c (and h copy) ----
    float c_reg = c0[b * HID + u];
    float hv    = h0[b * HID + u];
    if (t < HID) {
        float h = h0[b * HID + t];
        _Float16 hh = (_Float16)h;
        h16s[0][t] = hh;
        h16s[1][t] = (_Float16)(h - (float)hh);
    }
    __syncthreads();
    if (tf_byte_mode) {
        const unsigned char* tb = (const unsigned char*)tf_raw;
        for (int s = t; s < MAXLEN; s += NT) tf8[s] = (tb[s] != 0);
    } else {
        const int* ti = (const int*)tf_raw;
        for (int s = t; s < MAXLEN; s += NT) tf8[s] = (ti[s] != 0);
    }
    __syncthreads();

    float* outlp = out + (size_t)b * MAXLEN * OUT;

    for (int s = 0; s < MAXLEN; s++) {
        // ---- phase 1: MFMA gates(s) in-register + logits(s-1) partials ----
        float4v acc0 = {0.f, 0.f, 0.f, 0.f};
        float4v acc1 = {0.f, 0.f, 0.f, 0.f};
        float4v lacc = {0.f, 0.f, 0.f, 0.f};
        #pragma unroll
        for (int kc = 0; kc < 4; kc++) {
            const half8 ahi = *(const half8*)&h16s[0][kc * 32 + quad * 8];
            const half8 alo = *(const half8*)&h16s[1][kc * 32 + quad * 8];
            acc0 = __builtin_amdgcn_mfma_f32_16x16x32_f16(ahi, B0hi[kc], acc0, 0, 0, 0);
            acc0 = __builtin_amdgcn_mfma_f32_16x16x32_f16(ahi, B0lo[kc], acc0, 0, 0, 0);
            acc0 = __builtin_amdgcn_mfma_f32_16x16x32_f16(alo, B0hi[kc], acc0, 0, 0, 0);
            acc1 = __builtin_amdgcn_mfma_f32_16x16x32_f16(ahi, B1hi[kc], acc1, 0, 0, 0);
            acc1 = __builtin_amdgcn_mfma_f32_16x16x32_f16(ahi, B1lo[kc], acc1, 0, 0, 0);
            acc1 = __builtin_amdgcn_mfma_f32_16x16x32_f16(alo, B1hi[kc], acc1, 0, 0, 0);
            if (wv < 2 && (kc >> 1) == wv) {
                const int c = kc & 1;
                lacc = __builtin_amdgcn_mfma_f32_16x16x32_f16(ahi, BLhi[c], lacc, 0, 0, 0);
                lacc = __builtin_amdgcn_mfma_f32_16x16x32_f16(ahi, BLlo[c], lacc, 0, 0, 0);
                lacc = __builtin_amdgcn_mfma_f32_16x16x32_f16(alo, BLhi[c], lacc, 0, 0, 0);
            }
        }
        if (wv < 2 && quad == 0 && mrow < 8) lp[wv][mrow] = lacc[0];
        __syncthreads();   // A: lp ready; everyone's h16s reads done

        // ---- phase 2: every lane computes argmax/xsel locally (no serial tail) ----
        int xsel;
        if (s > 0) {
            float lg[OUT];
            #pragma unroll
            for (int j = 0; j < OUT; j++) lg[j] = lp[0][j] + lp[1][j] + boutr[j];
            float bv = lg[0]; int bi = 0;
            #pragma unroll
            for (int j = 1; j < OUT; j++) if (lg[j] > bv) { bv = lg[j]; bi = j; }
            xsel = tf8[s - 1] ? (int)tgt8[s - 1] : bi;
            if (wv == 2 && quad == 0 && mrow < OUT)
                ring[(s - 1) & (RINGD - 1)][mrow] = lg[mrow];
        } else {
            xsel = OUT - 1;
        }

        // ---- bulk flush (every 256 steps; range ends at s-2: slot-disjoint
        //      from this step's ring write, so no extra barrier needed) ----
        if ((s & 255) == 1 && s > 256 && t < 256) {
            const int step = (s - 257) + t;
            const int slot = step & (RINGD - 1);
            float v[OUT];
            #pragma unroll
            for (int j = 0; j < OUT; j++) v[j] = ring[slot][j];
            float mx = v[0];
            #pragma unroll
            for (int j = 1; j < OUT; j++) mx = fmaxf(mx, v[j]);
            float sum = 0.f;
            #pragma unroll
            for (int j = 0; j < OUT; j++) sum += __expf(v[j] - mx);
            const float lse = mx + __logf(sum);
            float* dst = outlp + (size_t)step * OUT;
            #pragma unroll
            for (int j = 0; j < OUT; j++) dst[j] = v[j] - lse;
        }

        // ---- in-register pointwise: gather own unit's 4 gates via shfl ----
        const int srcq = lane & 48;      // stay within own quad-row copy
        float gi = __shfl(acc0[0], srcq + m, 64);
        float gf = __shfl(acc0[0], srcq + m + 8, 64);
        float gg = __shfl(acc1[0], srcq + m, 64);
        float go = __shfl(acc1[0], srcq + m + 8, 64);
        const int xo = xsel * NG;
        float ri = gi + wih_eff[xo + u];
        float rf = gf + wih_eff[xo + HID + u];
        float rg = gg + wih_eff[xo + 2 * HID + u];
        float ro = go + wih_eff[xo + 3 * HID + u];
        float cn = sigm_(rf) * c_reg + sigm_(ri) * tanh_(rg);
        c_reg = cn;
        hv = sigm_(ro) * tanh_(cn);
        if (quad == 0 && mrow < 8) {
            _Float16 hh = (_Float16)hv;
            h16s[0][u] = hh;
            h16s[1][u] = (_Float16)(hv - (float)hh);
        }
        __syncthreads();   // C: h(s+1) staged
    }

    // ---- epilogue: logits for step 2047 from final h ----
    {
        float4v lacc = {0.f, 0.f, 0.f, 0.f};
        if (wv < 2) {
            #pragma unroll
            for (int c = 0; c < 2; c++) {
                const int kc = wv * 2 + c;
                const half8 ahi = *(const half8*)&h16s[0][kc * 32 + quad * 8];
                const half8 alo = *(const half8*)&h16s[1][kc * 32 + quad * 8];
                lacc = __builtin_amdgcn_mfma_f32_16x16x32_f16(ahi, BLhi[c], lacc, 0, 0, 0);
                lacc = __builtin_amdgcn_mfma_f32_16x16x32_f16(ahi, BLlo[c], lacc, 0, 0, 0);
                lacc = __builtin_amdgcn_mfma_f32_16x16x32_f16(alo, BLhi[c], lacc, 0, 0, 0);
            }
            if (quad == 0 && mrow < 8) lp[wv][mrow] = lacc[0];
        }
    }
    __syncthreads();
    if (wv == 2 && quad == 0 && mrow < OUT)
        ring[(MAXLEN - 1) & (RINGD - 1)][mrow] = lp[0][mrow] + lp[1][mrow] + boutr[mrow];
    __syncthreads();
    if (t < 256) {   // final flush: steps 1792..2047
        const int step = (MAXLEN - 256) + t;
        const int slot = step & (RINGD - 1);
        float v[OUT];
        #pragma unroll
        for (int j = 0; j < OUT; j++) v[j] = ring[slot][j];
        float mx = v[0];
        #pragma unroll
        for (int j = 1; j < OUT; j++) mx = fmaxf(mx, v[j]);
        float sum = 0.f;
        #pragma unroll
        for (int j = 0; j < OUT; j++) sum += __expf(v[j] - mx);
        const float lse = mx + __logf(sum);
        float* dst = outlp + (size_t)step * OUT;
        #pragma unroll
        for (int j = 0; j < OUT; j++) dst[j] = v[j] - lse;
    }
    if (quad == 0 && mrow < 8) {     // 16 waves x 8 units = full fp32 state
        out[OFF_STATE + b * HID + u] = hv;
        out[OFF_STATE + BATCH * HID + b * HID + u] = c_reg;
    }
}

extern "C" void kernel_launch(void* const* d_in, const int* in_sizes, int n_in,
                              void* d_out, int out_size, void* d_ws, size_t ws_size,
                              hipStream_t stream) {
    const float* h0    = (const float*)d_in[0];
    const float* c0    = (const float*)d_in[1];
    const float* toh   = (const float*)d_in[2];
    const void*  tfm   = (const void*) d_in[3];
    const float* Wih   = (const float*)d_in[4];
    const float* Whh   = (const float*)d_in[5];
    const float* bih   = (const float*)d_in[6];
    const float* bhh   = (const float*)d_in[7];
    const float* Wout  = (const float*)d_in[8];
    const float* bout  = (const float*)d_in[9];
    float* out = (float*)d_out;

    decoder_rnn_kernel<<<dim3(BATCH), dim3(NT), 0, stream>>>(
        h0, c0, toh, tfm, Wih, Whh, bih, bhh, Wout, bout, out);
}

// Round 17
// 2945.373 us; speedup vs baseline: 1.3360x; 1.3360x over previous
//
#include <hip/hip_runtime.h>
#include <math.h>

#define BATCH 10
#define HID 128
#define OUT 7
#define MAXLEN 2048
#define NG 512
#define NT 1024
#define RINGD 512
#define OFF_STATE ((size_t)BATCH * MAXLEN * OUT)

typedef _Float16 half8 __attribute__((ext_vector_type(8)));
typedef float float4v __attribute__((ext_vector_type(4)));

__device__ __forceinline__ float sigm_(float x) { return 1.0f / (1.0f + __expf(-x)); }
__device__ __forceinline__ float tanh_(float x) { return 1.0f - 2.0f / (1.0f + __expf(2.0f * x)); }

__global__
__attribute__((amdgpu_flat_work_group_size(NT, NT), amdgpu_waves_per_eu(4, 4)))
void decoder_rnn_kernel(const float* __restrict__ h0,
                        const float* __restrict__ c0,
                        const float* __restrict__ tonehot,   // (MAXLEN+1, 1, OUT)
                        const void*  __restrict__ tf_raw,    // bool mask, int8 or int32
                        const float* __restrict__ Wih,       // (4H, OUT)
                        const float* __restrict__ Whh,       // (4H, H)
                        const float* __restrict__ bih,
                        const float* __restrict__ bhh,
                        const float* __restrict__ Wout,      // (OUT, H)
                        const float* __restrict__ bout,
                        float* __restrict__ out)
{
    // 1 chain per block (R15 base). 2 barriers/step; argmax folded into the
    // 2-wave pointwise; MFMA accumulator chains split 12-deep -> 4-deep.
    __shared__ __align__(16) _Float16 h16s[2][HID];      // h hi/lo f16 split
    __shared__ float gates_lds[NG];                      // MFMA D: pre-bias gates
    __shared__ float wih_eff[OUT * NG];                  // Wih^T + bias, [x][g]
    __shared__ float ring[RINGD][OUT];                   // raw biased logits
    __shared__ float lp[2][8];                           // logits K-partials
    __shared__ unsigned char tgt8[MAXLEN];
    __shared__ unsigned char tf8[MAXLEN];
    __shared__ int tf_byte_mode;

    const int t    = threadIdx.x;
    const int lane = t & 63;
    const int wv   = t >> 6;       // wave 0..15 -> gate cols wv*32 .. wv*32+31
    const int quad = lane >> 4;
    const int mrow = lane & 15;
    const int b    = blockIdx.x;

    // ---- B-fragments (W_hh) in registers (AGPR-resident), f16 hi/lo split ----
    half8 Bhi[2][4], Blo[2][4];
    {
        const int g0 = wv * 32 + mrow;
        const int g1 = g0 + 16;
        #pragma unroll
        for (int kc = 0; kc < 4; kc++) {
            const int kb = kc * 32 + quad * 8;
            const float* p0 = Whh + (size_t)g0 * HID + kb;
            const float* p1 = Whh + (size_t)g1 * HID + kb;
            #pragma unroll
            for (int j = 0; j < 8; j++) {
                float w0 = p0[j];
                _Float16 w0h = (_Float16)w0;
                Bhi[0][kc][j] = w0h;
                Blo[0][kc][j] = (_Float16)(w0 - (float)w0h);
                float w1 = p1[j];
                _Float16 w1h = (_Float16)w1;
                Bhi[1][kc][j] = w1h;
                Blo[1][kc][j] = (_Float16)(w1 - (float)w1h);
            }
        }
    }
    // logits B-tile (Wout rows as cols), K-split: wave0 kc 0-1, wave1 kc 2-3
    half8 BLhi[2], BLlo[2];
    {
        #pragma unroll
        for (int c = 0; c < 2; c++)
            #pragma unroll
            for (int j = 0; j < 8; j++) { BLhi[c][j] = (_Float16)0; BLlo[c][j] = (_Float16)0; }
        if (wv < 2 && mrow < OUT) {
            #pragma unroll
            for (int c = 0; c < 2; c++) {
                const int kb = (wv * 2 + c) * 32 + quad * 8;
                const float* p = Wout + (size_t)mrow * HID + kb;
                #pragma unroll
                for (int j = 0; j < 8; j++) {
                    float w = p[j];
                    _Float16 wh = (_Float16)w;
                    BLhi[c][j] = wh;
                    BLlo[c][j] = (_Float16)(w - (float)wh);
                }
            }
        }
    }

    float boutr[OUT];
    #pragma unroll
    for (int j = 0; j < OUT; j++) boutr[j] = bout[j];

    // ---- LDS setup ----
    for (int idx = t; idx < OUT * NG; idx += NT) {
        int x = idx >> 9, g = idx & (NG - 1);
        wih_eff[idx] = Wih[g * OUT + x] + bih[g] + bhh[g];
    }
    if (t == 0) tf_byte_mode = 0;
    for (int s = t; s < MAXLEN; s += NT) {
        const float* row = tonehot + (size_t)(s + 1) * OUT;
        int idx = 0;
        #pragma unroll
        for (int j = 0; j < OUT; j++) if (row[j] > 0.5f) idx = j;
        tgt8[s] = (unsigned char)idx;
    }
    __syncthreads();
    {   // tf_mask layout detection (int8 bool vs int32) — proven R1-R16
        const unsigned char* tb = (const unsigned char*)tf_raw;
        int mis = 0;
        for (int p = t; p < MAXLEN; p += NT)
            if ((p & 3) && tb[p]) mis = 1;
        if (mis) atomicOr(&tf_byte_mode, 1);
    }
    // ---- state init ----
    float c_reg = 0.f, hv = 0.f;
    if (t < HID) {
        hv    = h0[b * HID + t];
        c_reg = c0[b * HID + t];
        _Float16 hh = (_Float16)hv;
        h16s[0][t] = hh;
        h16s[1][t] = (_Float16)(hv - (float)hh);
    }
    __syncthreads();
    if (tf_byte_mode) {
        const unsigned char* tb = (const unsigned char*)tf_raw;
        for (int s = t; s < MAXLEN; s += NT) tf8[s] = (tb[s] != 0);
    } else {
        const int* ti = (const int*)tf_raw;
        for (int s = t; s < MAXLEN; s += NT) tf8[s] = (ti[s] != 0);
    }
    __syncthreads();

    float* outlp = out + (size_t)b * MAXLEN * OUT;

    for (int s = 0; s < MAXLEN; s++) {
        // ---- phase 1: MFMA gates(s) + logits(s-1), chains split 3-way ----
        float4v p0 = {0,0,0,0}, q0 = {0,0,0,0}, r0 = {0,0,0,0};
        float4v p1 = {0,0,0,0}, q1 = {0,0,0,0}, r1 = {0,0,0,0};
        float4v lA = {0,0,0,0}, lB = {0,0,0,0};
        #pragma unroll
        for (int kc = 0; kc < 4; kc++) {
            const half8 ahi = *(const half8*)&h16s[0][kc * 32 + quad * 8];
            const half8 alo = *(const half8*)&h16s[1][kc * 32 + quad * 8];
            p0 = __builtin_amdgcn_mfma_f32_16x16x32_f16(ahi, Bhi[0][kc], p0, 0, 0, 0);
            q0 = __builtin_amdgcn_mfma_f32_16x16x32_f16(ahi, Blo[0][kc], q0, 0, 0, 0);
            r0 = __builtin_amdgcn_mfma_f32_16x16x32_f16(alo, Bhi[0][kc], r0, 0, 0, 0);
            p1 = __builtin_amdgcn_mfma_f32_16x16x32_f16(ahi, Bhi[1][kc], p1, 0, 0, 0);
            q1 = __builtin_amdgcn_mfma_f32_16x16x32_f16(ahi, Blo[1][kc], q1, 0, 0, 0);
            r1 = __builtin_amdgcn_mfma_f32_16x16x32_f16(alo, Bhi[1][kc], r1, 0, 0, 0);
            if (wv < 2 && (kc >> 1) == wv) {
                const int c = kc & 1;
                lA = __builtin_amdgcn_mfma_f32_16x16x32_f16(ahi, BLhi[c], lA, 0, 0, 0);
                lB = __builtin_amdgcn_mfma_f32_16x16x32_f16(ahi, BLlo[c], lB, 0, 0, 0);
                lB = __builtin_amdgcn_mfma_f32_16x16x32_f16(alo, BLhi[c], lB, 0, 0, 0);
            }
        }
        // every D row identical (all A rows = h): quad 0 extracts reg 0
        if (quad == 0) {
            gates_lds[wv * 32 + mrow]      = (p0[0] + q0[0]) + r0[0];
            gates_lds[wv * 32 + 16 + mrow] = (p1[0] + q1[0]) + r1[0];
        }
        if (wv < 2 && quad == 0 && mrow < 8) lp[wv][mrow] = lA[0] + lB[0];
        __syncthreads();   // A: gates + lp ready; h16s reads done

        // ---- phase 2a: pointwise waves (t<128) do argmax+xsel locally ----
        if (t < HID) {
            int xsel = OUT - 1;
            if (s > 0) {
                float lg[OUT];
                #pragma unroll
                for (int j = 0; j < OUT; j++) lg[j] = lp[0][j] + lp[1][j] + boutr[j];
                float bv = lg[0]; int bi = 0;
                #pragma unroll
                for (int j = 1; j < OUT; j++) if (lg[j] > bv) { bv = lg[j]; bi = j; }
                xsel = tf8[s - 1] ? (int)tgt8[s - 1] : bi;
                if (t < OUT) ring[(s - 1) & (RINGD - 1)][t] = lg[t];
            }
            const int xo = xsel * NG;
            float ri = gates_lds[t]           + wih_eff[xo + t];
            float rf = gates_lds[HID + t]     + wih_eff[xo + HID + t];
            float rg = gates_lds[2 * HID + t] + wih_eff[xo + 2 * HID + t];
            float ro = gates_lds[3 * HID + t] + wih_eff[xo + 3 * HID + t];
            float cn = sigm_(rf) * c_reg + sigm_(ri) * tanh_(rg);
            c_reg = cn;
            hv = sigm_(ro) * tanh_(cn);
            _Float16 hh = (_Float16)hv;
            h16s[0][t] = hh;
            h16s[1][t] = (_Float16)(hv - (float)hh);
        } else if (t >= 512 && t < 512 + 256 && (s & 255) == 1 && s > 256) {
            // ---- phase 2b: deferred log-softmax flush (waves 8-11) ----
            const int step = (s - 257) + (t - 512);      // slot-disjoint from (s-1)
            const int slot = step & (RINGD - 1);
            float v[OUT];
            #pragma unroll
            for (int j = 0; j < OUT; j++) v[j] = ring[slot][j];
            float mx = v[0];
            #pragma unroll
            for (int j = 1; j < OUT; j++) mx = fmaxf(mx, v[j]);
            float sum = 0.f;
            #pragma unroll
            for (int j = 0; j < OUT; j++) sum += __expf(v[j] - mx);
            const float lse = mx + __logf(sum);
            float* dst = outlp + (size_t)step * OUT;
            #pragma unroll
            for (int j = 0; j < OUT; j++) dst[j] = v[j] - lse;
        }
        __syncthreads();   // C: h(s+1) staged
    }

    // ---- epilogue: logits for step 2047 from final h ----
    if (wv < 2) {
        float4v lA = {0,0,0,0}, lB = {0,0,0,0};
        #pragma unroll
        for (int c = 0; c < 2; c++) {
            const int kc = wv * 2 + c;
            const half8 ahi = *(const half8*)&h16s[0][kc * 32 + quad * 8];
            const half8 alo = *(const half8*)&h16s[1][kc * 32 + quad * 8];
            lA = __builtin_amdgcn_mfma_f32_16x16x32_f16(ahi, BLhi[c], lA, 0, 0, 0);
            lB = __builtin_amdgcn_mfma_f32_16x16x32_f16(ahi, BLlo[c], lB, 0, 0, 0);
            lB = __builtin_amdgcn_mfma_f32_16x16x32_f16(alo, BLhi[c], lB, 0, 0, 0);
        }
        if (quad == 0 && mrow < 8) lp[wv][mrow] = lA[0] + lB[0];
    }
    __syncthreads();
    if (t < OUT)
        ring[(MAXLEN - 1) & (RINGD - 1)][t] = lp[0][t] + lp[1][t] + boutr[t];
    __syncthreads();
    if (t < 256) {   // final flush: steps 1792..2047
        const int step = (MAXLEN - 256) + t;
        const int slot = step & (RINGD - 1);
        float v[OUT];
        #pragma unroll
        for (int j = 0; j < OUT; j++) v[j] = ring[slot][j];
        float mx = v[0];
        #pragma unroll
        for (int j = 1; j < OUT; j++) mx = fmaxf(mx, v[j]);
        float sum = 0.f;
        #pragma unroll
        for (int j = 0; j < OUT; j++) sum += __expf(v[j] - mx);
        const float lse = mx + __logf(sum);
        float* dst = outlp + (size_t)step * OUT;
        #pragma unroll
        for (int j = 0; j < OUT; j++) dst[j] = v[j] - lse;
    }
    if (t < HID) {
        out[OFF_STATE + b * HID + t] = hv;                        // hT
        out[OFF_STATE + BATCH * HID + b * HID + t] = c_reg;       // cT
    }
}

extern "C" void kernel_launch(void* const* d_in, const int* in_sizes, int n_in,
                              void* d_out, int out_size, void* d_ws, size_t ws_size,
                              hipStream_t stream) {
    const float* h0    = (const float*)d_in[0];
    const float* c0    = (const float*)d_in[1];
    const float* toh   = (const float*)d_in[2];
    const void*  tfm   = (const void*) d_in[3];
    const float* Wih   = (const float*)d_in[4];
    const float* Whh   = (const float*)d_in[5];
    const float* bih   = (const float*)d_in[6];
    const float* bhh   = (const float*)d_in[7];
    const float* Wout  = (const float*)d_in[8];
    const float* bout  = (const float*)d_in[9];
    float* out = (float*)d_out;

    decoder_rnn_kernel<<<dim3(BATCH), dim3(NT), 0, stream>>>(
        h0, c0, toh, tfm, Wih, Whh, bih, bhh, Wout, bout, out);
}